// Round 1
// baseline (3218.970 us; speedup 1.0000x reference)
//
#include <hip/hip_runtime.h>
#include <math.h>

#define N4K 4096
#define BM 128
#define BN 128
#define BK 16

// Tables replicate the reference's fp32 expression order exactly:
//   w = f32(pi/8192) * (2*col_or_row + 1)  (fp32 mul)
//   angle = w * index                       (fp32 mul, NO mod-reduction)
//   cos(angle)                              (correctly-reduced cosf)
// so our table matches the JAX fp32 table to ~2 ulp even at large args.
// C [k][i] = cos(W*(2i+1)*k)   (rows = output freq u, used as GEMM-A)
// Ct[j][v] = cos(W*(2j+1)*v)   (= C1[v][j], used as GEMM-B for T @ C1^T)
__global__ __launch_bounds__(256) void gen_tables(float* __restrict__ C,
                                                  float* __restrict__ Ct) {
    const int idx = blockIdx.x * 256 + threadIdx.x;   // 4096 * 1024 threads
    const int r  = idx >> 10;
    const int c4 = (idx & 1023) << 2;
    const float W  = (float)(M_PI / 8192.0);
    const float fr = (float)r;
    const float wr = W * (float)(2 * r + 1);
    float4 a, b;
    float* ap = (float*)&a;
    float* bp = (float*)&b;
#pragma unroll
    for (int t = 0; t < 4; ++t) {
        const int c = c4 + t;
        const float wc = W * (float)(2 * c + 1);
        ap[t] = cosf(wc * fr);            // C[r][c]
        bp[t] = cosf(wr * (float)c);      // Ct[r][c]
    }
    *(float4*)(C  + (size_t)r * N4K + c4) = a;
    *(float4*)(Ct + (size_t)r * N4K + c4) = b;
}

// Plain row-major fp32 GEMM: D = A @ B, 4096^3.
// 128x128 tile, BK=16, 256 threads, each thread 8x8 as 2x2 quads of 4x4.
// As stored transposed [BK][BM+4]; pad +4 keeps 16B alignment and makes
// staging writes ~2-way (free) while reads stay conflict-free.
__global__ __launch_bounds__(256) void sgemm128(const float* __restrict__ A,
                                                const float* __restrict__ B,
                                                float* __restrict__ D) {
    __shared__ __align__(16) float As[BK][BM + 4];
    __shared__ __align__(16) float Bs[BK][BN];
    const int tid  = threadIdx.x;
    const int row0 = blockIdx.y * BM;
    const int col0 = blockIdx.x * BN;
    const int tx = tid & 15, ty = tid >> 4;

    float4 acc[2][2][4];
#pragma unroll
    for (int i = 0; i < 2; ++i)
#pragma unroll
        for (int j = 0; j < 2; ++j)
#pragma unroll
            for (int m = 0; m < 4; ++m)
                acc[i][j][m] = make_float4(0.f, 0.f, 0.f, 0.f);

    for (int k0 = 0; k0 < N4K; k0 += BK) {
        // ---- stage A (128x16, transposed into LDS) and B (16x128) ----
#pragma unroll
        for (int s = 0; s < 2; ++s) {
            const int v = tid + s * 256;
            const int ar = v >> 2, ac4 = (v & 3) << 2;
            const float4 av =
                *(const float4*)(A + (size_t)(row0 + ar) * N4K + k0 + ac4);
            As[ac4 + 0][ar] = av.x;
            As[ac4 + 1][ar] = av.y;
            As[ac4 + 2][ar] = av.z;
            As[ac4 + 3][ar] = av.w;
            const int br = v >> 5, bc4 = (v & 31) << 2;
            *(float4*)&Bs[br][bc4] =
                *(const float4*)(B + (size_t)(k0 + br) * N4K + col0 + bc4);
        }
        __syncthreads();
        // ---- compute 16 k-steps ----
#pragma unroll
        for (int k = 0; k < BK; ++k) {
            const float4 a0 = *(const float4*)&As[k][ty * 4];
            const float4 a1 = *(const float4*)&As[k][ty * 4 + 64];
            const float4 b0 = *(const float4*)&Bs[k][tx * 4];
            const float4 b1 = *(const float4*)&Bs[k][tx * 4 + 64];
            const float am[2][4] = {{a0.x, a0.y, a0.z, a0.w},
                                    {a1.x, a1.y, a1.z, a1.w}};
            const float4 bn[2] = {b0, b1};
#pragma unroll
            for (int mg = 0; mg < 2; ++mg)
#pragma unroll
                for (int ng = 0; ng < 2; ++ng)
#pragma unroll
                    for (int mi = 0; mi < 4; ++mi) {
                        acc[mg][ng][mi].x += am[mg][mi] * bn[ng].x;
                        acc[mg][ng][mi].y += am[mg][mi] * bn[ng].y;
                        acc[mg][ng][mi].z += am[mg][mi] * bn[ng].z;
                        acc[mg][ng][mi].w += am[mg][mi] * bn[ng].w;
                    }
        }
        __syncthreads();
    }

    // ---- epilogue: 16 coalesced float4 stores ----
#pragma unroll
    for (int mg = 0; mg < 2; ++mg)
#pragma unroll
        for (int mi = 0; mi < 4; ++mi) {
            const int row = row0 + mg * 64 + ty * 4 + mi;
#pragma unroll
            for (int ng = 0; ng < 2; ++ng) {
                const int col = col0 + ng * 64 + tx * 4;
                *(float4*)(D + (size_t)row * N4K + col) = acc[mg][ng][mi];
            }
        }
}

extern "C" void kernel_launch(void* const* d_in, const int* in_sizes, int n_in,
                              void* d_out, int out_size, void* d_ws, size_t ws_size,
                              hipStream_t stream) {
    const float* x = (const float*)d_in[0];
    float* out = (float*)d_out;
    // workspace layout: C (64MB) | Ct (64MB) | T (64MB)
    float* C  = (float*)d_ws;
    float* Ct = C  + (size_t)N4K * N4K;
    float* T  = Ct + (size_t)N4K * N4K;

    // 1) build cosine tables (both orientations) — ~16k blocks, trivial cost
    gen_tables<<<dim3((N4K * (N4K / 4)) / 256), 256, 0, stream>>>(C, Ct);

    // 2) T = C @ x          (DCT along rows dim)
    dim3 grid(N4K / BN, N4K / BM);
    sgemm128<<<grid, 256, 0, stream>>>(C, x, T);

    // 3) out = T @ Ct       (DCT along cols dim)
    sgemm128<<<grid, 256, 0, stream>>>(T, Ct, out);
}

// Round 2
// 1159.225 us; speedup vs baseline: 2.7768x; 2.7768x over previous
//
#include <hip/hip_runtime.h>
#include <math.h>

#define NN 4096

typedef __attribute__((ext_vector_type(8))) short short8;
typedef __attribute__((ext_vector_type(4))) float f32x4;
typedef unsigned int uint32;
typedef unsigned short ushort16_t;

__device__ __forceinline__ ushort16_t f2bf(float f) {
    uint32 u = __float_as_uint(f);
    return (ushort16_t)((u + 0x7FFFu + ((u >> 16) & 1u)) >> 16);  // RNE
}
__device__ __forceinline__ float bf2f(ushort16_t h) {
    return __uint_as_float(((uint32)h) << 16);
}

// async global->LDS, 16B per lane. LDS dest = wave-uniform base + lane*16.
__device__ __forceinline__ void gload_lds16(const unsigned short* g, unsigned short* l) {
    __builtin_amdgcn_global_load_lds(
        (const __attribute__((address_space(1))) uint32*)g,
        (__attribute__((address_space(3))) uint32*)l, 16, 0, 0);
}

// ---- cosine table, bf16 hi/lo split. Same fp32 expression order as the
// validated round-0 table: angle = (W*(2c+1)) * r, then cosf. ----
// Ctab[r][c] = cos(W*(2c+1)*r). Used as A in GEMM1 (r=u,c=i) and as
// Bt in GEMM2 (r=v,c=j) — same matrix both times.
__global__ __launch_bounds__(256) void gen_tables(unsigned short* __restrict__ Chi,
                                                  unsigned short* __restrict__ Clo) {
    const int idx = blockIdx.x * 256 + threadIdx.x;
    const int r  = idx >> 10;
    const int c4 = (idx & 1023) << 2;
    const float W  = (float)(M_PI / 8192.0);
    const float fr = (float)r;
    ushort4 hv, lv;
    unsigned short* hp = (unsigned short*)&hv;
    unsigned short* lp = (unsigned short*)&lv;
#pragma unroll
    for (int t = 0; t < 4; ++t) {
        const int c = c4 + t;
        const float wc = W * (float)(2 * c + 1);
        const float v = cosf(wc * fr);
        const ushort16_t h = f2bf(v);
        hp[t] = h;
        lp[t] = f2bf(v - bf2f(h));
    }
    *(ushort4*)(Chi + (size_t)r * NN + c4) = hv;
    *(ushort4*)(Clo + (size_t)r * NN + c4) = lv;
}

// ---- transpose + hi/lo split of x: xt*[j][i] = split(x[i][j]) ----
__global__ __launch_bounds__(256) void transpose_split(const float* __restrict__ x,
                                                       unsigned short* __restrict__ xthi,
                                                       unsigned short* __restrict__ xtlo) {
    __shared__ float tile[64][65];
    const int tid = threadIdx.x;
    const int r0 = blockIdx.y * 64, c0 = blockIdx.x * 64;
    const int tr = tid >> 4, tc4 = (tid & 15) * 4;
#pragma unroll
    for (int p = 0; p < 4; ++p) {
        const int row = p * 16 + tr;
        const float4 v = *(const float4*)(x + (size_t)(r0 + row) * NN + c0 + tc4);
        tile[row][tc4 + 0] = v.x;
        tile[row][tc4 + 1] = v.y;
        tile[row][tc4 + 2] = v.z;
        tile[row][tc4 + 3] = v.w;
    }
    __syncthreads();
#pragma unroll
    for (int p = 0; p < 4; ++p) {
        const int jj = p * 16 + tr;   // output row within tile (= input col)
        ushort4 hv, lv;
        unsigned short* hp = (unsigned short*)&hv;
        unsigned short* lp = (unsigned short*)&lv;
#pragma unroll
        for (int q = 0; q < 4; ++q) {
            const float v = tile[tc4 + q][jj];
            const ushort16_t h = f2bf(v);
            hp[q] = h;
            lp[q] = f2bf(v - bf2f(h));
        }
        const size_t o = (size_t)(c0 + jj) * NN + r0 + tc4;
        *(ushort4*)(xthi + o) = hv;
        *(ushort4*)(xtlo + o) = lv;
    }
}

// ---- bf16x3 GEMM, m97 structure: D = sum_t A_t (MxK, row-major) * B_t^T
// where B_t is stored N-major [n][k]. 128x128 tile, BK=32, 4 waves (2x2),
// each wave 64x64 = 4x4 fragments of 16x16x32 MFMA.
// LDS linear for global_load_lds; 4-way-conflict XOR swizzle applied by
// pre-swizzling the per-lane GLOBAL source address (m173 pattern).
template <int SPLIT>
__global__ __launch_bounds__(256) void gemm_bf16x3(
    const unsigned short* __restrict__ A0, const unsigned short* __restrict__ B0,
    const unsigned short* __restrict__ A1, const unsigned short* __restrict__ B1,
    const unsigned short* __restrict__ A2, const unsigned short* __restrict__ B2,
    float* __restrict__ Dout,
    unsigned short* __restrict__ Dhi, unsigned short* __restrict__ Dlo) {
    __shared__ unsigned short Al[128 * 32];   // [row][32k], 16B chunks XOR-swizzled
    __shared__ unsigned short Bl[128 * 32];
    const int tid = threadIdx.x;
    const int w = tid >> 6, l = tid & 63;
    const int wr = w >> 1, wc = w & 1;
    const int lrow = l & 15, kh = l >> 4;     // kh = K-half index (0..3)
    const int row0 = blockIdx.y * 128, col0 = blockIdx.x * 128;

    f32x4 acc[4][4];
#pragma unroll
    for (int i = 0; i < 4; ++i)
#pragma unroll
        for (int j = 0; j < 4; ++j)
            acc[i][j] = (f32x4){0.f, 0.f, 0.f, 0.f};

    // staging geometry: 16B slot v = s*256 + tid; row = v>>2,
    // logical k-chunk stored at phys chunk (v&3) is ((v&3) ^ (row&3)).
    const int v0 = tid, v1 = tid + 256;
    const int ar0 = v0 >> 2, ac0 = ((v0 & 3) ^ (ar0 & 3)) * 8;
    const int ar1 = v1 >> 2, ac1 = ((v1 & 3) ^ (ar1 & 3)) * 8;
    unsigned short* ldsA0 = &Al[(size_t)(0 * 256 + w * 64) * 8];
    unsigned short* ldsA1 = &Al[(size_t)(1 * 256 + w * 64) * 8];
    unsigned short* ldsB0 = &Bl[(size_t)(0 * 256 + w * 64) * 8];
    unsigned short* ldsB1 = &Bl[(size_t)(1 * 256 + w * 64) * 8];

#pragma unroll
    for (int t = 0; t < 3; ++t) {
        const unsigned short* Ag = (t == 0) ? A0 : (t == 1) ? A1 : A2;
        const unsigned short* Bg = (t == 0) ? B0 : (t == 1) ? B1 : B2;
        const unsigned short* Asrc0 = Ag + (size_t)(row0 + ar0) * NN + ac0;
        const unsigned short* Asrc1 = Ag + (size_t)(row0 + ar1) * NN + ac1;
        const unsigned short* Bsrc0 = Bg + (size_t)(col0 + ar0) * NN + ac0;
        const unsigned short* Bsrc1 = Bg + (size_t)(col0 + ar1) * NN + ac1;
        for (int k0 = 0; k0 < NN; k0 += 32) {
            gload_lds16(Asrc0 + k0, ldsA0);
            gload_lds16(Asrc1 + k0, ldsA1);
            gload_lds16(Bsrc0 + k0, ldsB0);
            gload_lds16(Bsrc1 + k0, ldsB1);
            __syncthreads();   // drains vmcnt -> tile complete for all waves
            short8 af[4], bf[4];
#pragma unroll
            for (int f = 0; f < 4; ++f) {
                const int arow = wr * 64 + f * 16 + lrow;
                af[f] = *(const short8*)&Al[arow * 32 + ((kh ^ (arow & 3)) * 8)];
                const int brow = wc * 64 + f * 16 + lrow;
                bf[f] = *(const short8*)&Bl[brow * 32 + ((kh ^ (brow & 3)) * 8)];
            }
#pragma unroll
            for (int fm = 0; fm < 4; ++fm)
#pragma unroll
                for (int fn = 0; fn < 4; ++fn)
                    acc[fm][fn] = __builtin_amdgcn_mfma_f32_16x16x32_bf16(
                        af[fm], bf[fn], acc[fm][fn], 0, 0, 0);
            __syncthreads();   // before next stage overwrites LDS
        }
    }

    // epilogue: D row = row0 + wr*64 + fm*16 + kh*4 + m, col = col0 + wc*64 + fn*16 + lrow
#pragma unroll
    for (int fm = 0; fm < 4; ++fm) {
#pragma unroll
        for (int fn = 0; fn < 4; ++fn) {
#pragma unroll
            for (int m = 0; m < 4; ++m) {
                const int row = row0 + wr * 64 + fm * 16 + kh * 4 + m;
                const int col = col0 + wc * 64 + fn * 16 + lrow;
                const float f = acc[fm][fn][m];
                if (SPLIT) {
                    const ushort16_t h = f2bf(f);
                    Dhi[(size_t)row * NN + col] = h;
                    Dlo[(size_t)row * NN + col] = f2bf(f - bf2f(h));
                } else {
                    Dout[(size_t)row * NN + col] = f;
                }
            }
        }
    }
}

extern "C" void kernel_launch(void* const* d_in, const int* in_sizes, int n_in,
                              void* d_out, int out_size, void* d_ws, size_t ws_size,
                              hipStream_t stream) {
    const float* x = (const float*)d_in[0];
    float* out = (float*)d_out;
    // workspace: 6 x 32MB = 192MB (same footprint round 0 used successfully)
    unsigned short* Chi  = (unsigned short*)d_ws;
    unsigned short* Clo  = Chi  + (size_t)NN * NN;
    unsigned short* xthi = Clo  + (size_t)NN * NN;
    unsigned short* xtlo = xthi + (size_t)NN * NN;
    unsigned short* Thi  = xtlo + (size_t)NN * NN;
    unsigned short* Tlo  = Thi  + (size_t)NN * NN;

    gen_tables<<<dim3((NN * (NN / 4)) / 256), 256, 0, stream>>>(Chi, Clo);
    transpose_split<<<dim3(NN / 64, NN / 64), 256, 0, stream>>>(x, xthi, xtlo);

    dim3 grid(NN / 128, NN / 128);
    // GEMM1: T[u][j] = sum_i C[u][i] * x[i][j];  A=Ctab, Bt=x^T. Split-write T.
    gemm_bf16x3<1><<<grid, 256, 0, stream>>>(Chi, xthi, Clo, xthi, Chi, xtlo,
                                             nullptr, Thi, Tlo);
    // GEMM2: out[u][v] = sum_j T[u][j] * Ctab[v][j];  A=T, Bt=Ctab. fp32 out.
    gemm_bf16x3<0><<<grid, 256, 0, stream>>>(Thi, Chi, Tlo, Chi, Thi, Clo,
                                             out, nullptr, nullptr);
}

// Round 5
// 892.115 us; speedup vs baseline: 3.6082x; 1.2994x over previous
//
#include <hip/hip_runtime.h>
#include <math.h>

#define NN 4096
#define NT 128   // K tiles of 32

typedef __attribute__((ext_vector_type(8))) short short8;
typedef __attribute__((ext_vector_type(4))) float f32x4;
typedef unsigned int uint32;
typedef unsigned short u16;

__device__ __forceinline__ u16 f2bf(float f) {
    uint32 u = __float_as_uint(f);
    return (u16)((u + 0x7FFFu + ((u >> 16) & 1u)) >> 16);  // RNE
}
__device__ __forceinline__ float bf2f(u16 h) {
    return __uint_as_float(((uint32)h) << 16);
}

__device__ __forceinline__ void gload_lds16(const u16* g, u16* l) {
    __builtin_amdgcn_global_load_lds(
        (const __attribute__((address_space(1))) uint32*)g,
        (__attribute__((address_space(3))) uint32*)l, 16, 0, 0);
}

// ---- cosine table, bf16 hi/lo split (validated expression order) ----
__global__ __launch_bounds__(256) void gen_tables(u16* __restrict__ Chi,
                                                  u16* __restrict__ Clo) {
    const int idx = blockIdx.x * 256 + threadIdx.x;
    const int r  = idx >> 10;
    const int c4 = (idx & 1023) << 2;
    const float W  = (float)(M_PI / 8192.0);
    const float fr = (float)r;
    ushort4 hv, lv;
    u16* hp = (u16*)&hv;
    u16* lp = (u16*)&lv;
#pragma unroll
    for (int t = 0; t < 4; ++t) {
        const int c = c4 + t;
        const float wc = W * (float)(2 * c + 1);
        const float v = cosf(wc * fr);
        const u16 h = f2bf(v);
        hp[t] = h;
        lp[t] = f2bf(v - bf2f(h));
    }
    *(ushort4*)(Chi + (size_t)r * NN + c4) = hv;
    *(ushort4*)(Clo + (size_t)r * NN + c4) = lv;
}

// ---- transpose + hi/lo split of x (validated) ----
__global__ __launch_bounds__(256) void transpose_split(const float* __restrict__ x,
                                                       u16* __restrict__ xthi,
                                                       u16* __restrict__ xtlo) {
    __shared__ float tile[64][65];
    const int tid = threadIdx.x;
    const int r0 = blockIdx.y * 64, c0 = blockIdx.x * 64;
    const int tr = tid >> 4, tc4 = (tid & 15) * 4;
#pragma unroll
    for (int p = 0; p < 4; ++p) {
        const int row = p * 16 + tr;
        const float4 v = *(const float4*)(x + (size_t)(r0 + row) * NN + c0 + tc4);
        tile[row][tc4 + 0] = v.x;
        tile[row][tc4 + 1] = v.y;
        tile[row][tc4 + 2] = v.z;
        tile[row][tc4 + 3] = v.w;
    }
    __syncthreads();
#pragma unroll
    for (int p = 0; p < 4; ++p) {
        const int jj = p * 16 + tr;
        ushort4 hv, lv;
        u16* hp = (u16*)&hv;
        u16* lp = (u16*)&lv;
#pragma unroll
        for (int q = 0; q < 4; ++q) {
            const float v = tile[tc4 + q][jj];
            const u16 h = f2bf(v);
            hp[q] = h;
            lp[q] = f2bf(v - bf2f(h));
        }
        const size_t o = (size_t)(c0 + jj) * NN + r0 + tc4;
        *(ushort4*)(xthi + o) = hv;
        *(ushort4*)(xtlo + o) = lv;
    }
}

// ---- fused bf16x3 GEMM: D = Ahi*B + Alo*Bhi (B = Bhi+Blo), B stored N-major.
// 128x128 tile, BK=32, 4 waves (2x2), 64x64/wave of 16x16x32 MFMA.
// Double-buffered LDS (2 x {Ahi,Alo,Bhi,Blo} x 8KB = 64KB), raw s_barrier +
// counted vmcnt: 8 while a prefetch is in flight, 0 on the FINAL tile
// (round-4 bug: vmcnt(8) with only 8 outstanding was a no-op -> last K-tile
// computed on stale LDS. Epilogue must drain to 0.)
template <int SPLIT>
__global__ __launch_bounds__(256, 2) void gemm_fused3(
    const u16* __restrict__ Ahi, const u16* __restrict__ Alo,
    const u16* __restrict__ Bhi, const u16* __restrict__ Blo,
    float* __restrict__ Dout, u16* __restrict__ Dhi, u16* __restrict__ Dlo) {
    __shared__ u16 lds[2 * 4 * 4096];   // [buf][arr][128*32] = 64 KB
    const int tid = threadIdx.x;
    const int w = tid >> 6, l = tid & 63;
    const int wr = w >> 1, wc = w & 1;
    const int lrow = l & 15, kh = l >> 4;
    const int row0 = blockIdx.y * 128, col0 = blockIdx.x * 128;

    f32x4 acc[4][4];
#pragma unroll
    for (int i = 0; i < 4; ++i)
#pragma unroll
        for (int j = 0; j < 4; ++j)
            acc[i][j] = (f32x4){0.f, 0.f, 0.f, 0.f};

    // staging: 16B slot v = s*256+tid; row=v>>2; phys chunk (v&3) holds
    // logical k-chunk ((v&3) ^ (row&3))  -> read side XORs the same way.
    const int v0 = tid, v1 = tid + 256;
    const int r0s = v0 >> 2, c0s = ((v0 & 3) ^ (r0s & 3)) * 8;
    const int r1s = v1 >> 2, c1s = ((v1 & 3) ^ (r1s & 3)) * 8;
    const u16* pAhi0 = Ahi + (size_t)(row0 + r0s) * NN + c0s;
    const u16* pAhi1 = Ahi + (size_t)(row0 + r1s) * NN + c1s;
    const u16* pAlo0 = Alo + (size_t)(row0 + r0s) * NN + c0s;
    const u16* pAlo1 = Alo + (size_t)(row0 + r1s) * NN + c1s;
    const u16* pBhi0 = Bhi + (size_t)(col0 + r0s) * NN + c0s;
    const u16* pBhi1 = Bhi + (size_t)(col0 + r1s) * NN + c1s;
    const u16* pBlo0 = Blo + (size_t)(col0 + r0s) * NN + c0s;
    const u16* pBlo1 = Blo + (size_t)(col0 + r1s) * NN + c1s;
    const int d0 = (0 * 256 + w * 64) * 8;   // wave-uniform LDS dest (u16 idx)
    const int d1 = (1 * 256 + w * 64) * 8;

#define STAGE(buf, koff)                                                     \
    do {                                                                     \
        u16* Lb = &lds[(buf) * 16384];                                       \
        gload_lds16(pAhi0 + (koff), Lb + 0 * 4096 + d0);                     \
        gload_lds16(pAhi1 + (koff), Lb + 0 * 4096 + d1);                     \
        gload_lds16(pAlo0 + (koff), Lb + 1 * 4096 + d0);                     \
        gload_lds16(pAlo1 + (koff), Lb + 1 * 4096 + d1);                     \
        gload_lds16(pBhi0 + (koff), Lb + 2 * 4096 + d0);                     \
        gload_lds16(pBhi1 + (koff), Lb + 2 * 4096 + d1);                     \
        gload_lds16(pBlo0 + (koff), Lb + 3 * 4096 + d0);                     \
        gload_lds16(pBlo1 + (koff), Lb + 3 * 4096 + d1);                     \
    } while (0)

    STAGE(0, 0);   // prologue: tile 0 -> buf 0

    for (int t = 0; t < NT; ++t) {
        const int cur = t & 1;
        if (t + 1 < NT) {
            STAGE(cur ^ 1, (t + 1) * 32);
            // keep tile t+1's 8 loads in flight; retire tile t's 8
            asm volatile("s_waitcnt vmcnt(8)" ::: "memory");
        } else {
            // final tile: nothing in flight behind it -> full drain
            asm volatile("s_waitcnt vmcnt(0)" ::: "memory");
        }
        __builtin_amdgcn_s_barrier();
        asm volatile("" ::: "memory");

        const u16* Lb = &lds[cur * 16384];
        short8 ah[4], al[4], bh[4], bl[4];
#pragma unroll
        for (int f = 0; f < 4; ++f) {
            const int ar = wr * 64 + f * 16 + lrow;
            const int ao = ar * 32 + ((kh ^ (ar & 3)) * 8);
            ah[f] = *(const short8*)&Lb[0 * 4096 + ao];
            al[f] = *(const short8*)&Lb[1 * 4096 + ao];
            const int br = wc * 64 + f * 16 + lrow;
            const int bo = br * 32 + ((kh ^ (br & 3)) * 8);
            bh[f] = *(const short8*)&Lb[2 * 4096 + bo];
            bl[f] = *(const short8*)&Lb[3 * 4096 + bo];
        }
#pragma unroll
        for (int fm = 0; fm < 4; ++fm)
#pragma unroll
            for (int fn = 0; fn < 4; ++fn) {
                acc[fm][fn] = __builtin_amdgcn_mfma_f32_16x16x32_bf16(
                    ah[fm], bh[fn], acc[fm][fn], 0, 0, 0);
                acc[fm][fn] = __builtin_amdgcn_mfma_f32_16x16x32_bf16(
                    al[fm], bh[fn], acc[fm][fn], 0, 0, 0);
                acc[fm][fn] = __builtin_amdgcn_mfma_f32_16x16x32_bf16(
                    ah[fm], bl[fn], acc[fm][fn], 0, 0, 0);
            }
        // ds_reads of buf[cur] must complete before next iter re-stages it
        asm volatile("s_waitcnt lgkmcnt(0)" ::: "memory");
        __builtin_amdgcn_s_barrier();
        asm volatile("" ::: "memory");
    }
#undef STAGE

    // epilogue: row = row0+wr*64+fm*16+kh*4+m, col = col0+wc*64+fn*16+lrow
#pragma unroll
    for (int fm = 0; fm < 4; ++fm) {
#pragma unroll
        for (int fn = 0; fn < 4; ++fn) {
#pragma unroll
            for (int m = 0; m < 4; ++m) {
                const int row = row0 + wr * 64 + fm * 16 + kh * 4 + m;
                const int col = col0 + wc * 64 + fn * 16 + lrow;
                const float f = acc[fm][fn][m];
                if (SPLIT) {
                    const u16 h = f2bf(f);
                    Dhi[(size_t)row * NN + col] = h;
                    Dlo[(size_t)row * NN + col] = f2bf(f - bf2f(h));
                } else {
                    Dout[(size_t)row * NN + col] = f;
                }
            }
        }
    }
}

extern "C" void kernel_launch(void* const* d_in, const int* in_sizes, int n_in,
                              void* d_out, int out_size, void* d_ws, size_t ws_size,
                              hipStream_t stream) {
    const float* x = (const float*)d_in[0];
    float* out = (float*)d_out;
    u16* Chi  = (u16*)d_ws;
    u16* Clo  = Chi  + (size_t)NN * NN;
    u16* xthi = Clo  + (size_t)NN * NN;
    u16* xtlo = xthi + (size_t)NN * NN;
    u16* Thi  = xtlo + (size_t)NN * NN;
    u16* Tlo  = Thi  + (size_t)NN * NN;

    gen_tables<<<dim3((NN * (NN / 4)) / 256), 256, 0, stream>>>(Chi, Clo);
    transpose_split<<<dim3(NN / 64, NN / 64), 256, 0, stream>>>(x, xthi, xtlo);

    dim3 grid(NN / 128, NN / 128);
    // GEMM1: T = Ctab @ x           (A=Ctab hi/lo, B(n-major)=x^T hi/lo)
    gemm_fused3<1><<<grid, 256, 0, stream>>>(Chi, Clo, xthi, xtlo,
                                             nullptr, Thi, Tlo);
    // GEMM2: out = T @ Ctab^T       (A=T hi/lo, B(n-major)=Ctab hi/lo)
    gemm_fused3<0><<<grid, 256, 0, stream>>>(Thi, Tlo, Chi, Clo,
                                             out, nullptr, nullptr);
}

// Round 8
// 429.326 us; speedup vs baseline: 7.4977x; 2.0779x over previous
//
#include <hip/hip_runtime.h>
#include <math.h>

#define NN 4096
#define NT 128   // K tiles of 32

typedef __attribute__((ext_vector_type(8))) short short8;
typedef __attribute__((ext_vector_type(4))) float f32x4;
typedef unsigned int uint32;
typedef unsigned short u16;

__device__ __forceinline__ u16 f2bf(float f) {
    uint32 u = __float_as_uint(f);
    return (u16)((u + 0x7FFFu + ((u >> 16) & 1u)) >> 16);  // RNE
}

__device__ __forceinline__ void gload_lds16(const u16* g, u16* l) {
    __builtin_amdgcn_global_load_lds(
        (const __attribute__((address_space(1))) uint32*)g,
        (__attribute__((address_space(3))) uint32*)l, 16, 0, 0);
}

// ---- cosine table, bf16 (validated expression order, hi only) ----
// Ctab[r][c] = cos(W*(2c+1)*r); A-operand in GEMM1 (r=u,c=i),
// n-major B-operand in GEMM2 (r=v,c=j).
__global__ __launch_bounds__(256) void gen_tables(u16* __restrict__ Chi) {
    const int idx = blockIdx.x * 256 + threadIdx.x;
    const int r  = idx >> 10;
    const int c4 = (idx & 1023) << 2;
    const float W  = (float)(M_PI / 8192.0);
    const float fr = (float)r;
    ushort4 hv;
    u16* hp = (u16*)&hv;
#pragma unroll
    for (int t = 0; t < 4; ++t) {
        const int c = c4 + t;
        const float wc = W * (float)(2 * c + 1);
        hp[t] = f2bf(cosf(wc * fr));
    }
    *(ushort4*)(Chi + (size_t)r * NN + c4) = hv;
}

// ---- transpose + bf16 round of x: xt[j][i] = rnd(x[i][j]) ----
__global__ __launch_bounds__(256) void transpose_round(const float* __restrict__ x,
                                                       u16* __restrict__ xthi) {
    __shared__ float tile[64][65];
    const int tid = threadIdx.x;
    const int r0 = blockIdx.y * 64, c0 = blockIdx.x * 64;
    const int tr = tid >> 4, tc4 = (tid & 15) * 4;
#pragma unroll
    for (int p = 0; p < 4; ++p) {
        const int row = p * 16 + tr;
        const float4 v = *(const float4*)(x + (size_t)(r0 + row) * NN + c0 + tc4);
        tile[row][tc4 + 0] = v.x;
        tile[row][tc4 + 1] = v.y;
        tile[row][tc4 + 2] = v.z;
        tile[row][tc4 + 3] = v.w;
    }
    __syncthreads();
#pragma unroll
    for (int p = 0; p < 4; ++p) {
        const int jj = p * 16 + tr;
        ushort4 hv;
        u16* hp = (u16*)&hv;
#pragma unroll
        for (int q = 0; q < 4; ++q)
            hp[q] = f2bf(tile[tc4 + q][jj]);
        *(ushort4*)(xthi + (size_t)(c0 + jj) * NN + r0 + tc4) = hv;
    }
}

// ---- pure-bf16 GEMM: D = A (MxK row-major) * B^T (B stored n-major [n][k]).
// 128x128 tile, BK=32, 4 waves (2x2), 64x64/wave of 16x16x32 MFMA.
// Round-5-verified loop: dbuf LDS (2 x {A,B} x 8KB = 32KB), raw s_barrier +
// counted vmcnt(4) while prefetch in flight, vmcnt(0) on final tile.
template <int SPLIT>
__global__ __launch_bounds__(256, 4) void gemm_bf16(
    const u16* __restrict__ A, const u16* __restrict__ B,
    float* __restrict__ Dout, u16* __restrict__ Dhi) {
    __shared__ u16 lds[2 * 2 * 4096];   // [buf][arr][128*32] = 32 KB
    const int tid = threadIdx.x;
    const int w = tid >> 6, l = tid & 63;
    const int wr = w >> 1, wc = w & 1;
    const int lrow = l & 15, kh = l >> 4;
    const int row0 = blockIdx.y * 128, col0 = blockIdx.x * 128;

    f32x4 acc[4][4];
#pragma unroll
    for (int i = 0; i < 4; ++i)
#pragma unroll
        for (int j = 0; j < 4; ++j)
            acc[i][j] = (f32x4){0.f, 0.f, 0.f, 0.f};

    // staging: 16B slot v = s*256+tid; row=v>>2; phys chunk (v&3) holds
    // logical k-chunk ((v&3) ^ (row&3)); read side XORs the same way.
    const int v0 = tid, v1 = tid + 256;
    const int r0s = v0 >> 2, c0s = ((v0 & 3) ^ (r0s & 3)) * 8;
    const int r1s = v1 >> 2, c1s = ((v1 & 3) ^ (r1s & 3)) * 8;
    const u16* pA0 = A + (size_t)(row0 + r0s) * NN + c0s;
    const u16* pA1 = A + (size_t)(row0 + r1s) * NN + c1s;
    const u16* pB0 = B + (size_t)(col0 + r0s) * NN + c0s;
    const u16* pB1 = B + (size_t)(col0 + r1s) * NN + c1s;
    const int d0 = (0 * 256 + w * 64) * 8;   // wave-uniform LDS dest (u16 idx)
    const int d1 = (1 * 256 + w * 64) * 8;

#define STAGE(buf, koff)                                                     \
    do {                                                                     \
        u16* Lb = &lds[(buf) * 8192];                                        \
        gload_lds16(pA0 + (koff), Lb + 0 * 4096 + d0);                       \
        gload_lds16(pA1 + (koff), Lb + 0 * 4096 + d1);                       \
        gload_lds16(pB0 + (koff), Lb + 1 * 4096 + d0);                       \
        gload_lds16(pB1 + (koff), Lb + 1 * 4096 + d1);                       \
    } while (0)

    STAGE(0, 0);   // prologue: tile 0 -> buf 0

    for (int t = 0; t < NT; ++t) {
        const int cur = t & 1;
        if (t + 1 < NT) {
            STAGE(cur ^ 1, (t + 1) * 32);
            // retire tile t's 4 loads; keep tile t+1's 4 in flight
            asm volatile("s_waitcnt vmcnt(4)" ::: "memory");
        } else {
            // final tile: nothing behind it -> full drain (round-4 lesson)
            asm volatile("s_waitcnt vmcnt(0)" ::: "memory");
        }
        __builtin_amdgcn_s_barrier();
        asm volatile("" ::: "memory");

        const u16* Lb = &lds[cur * 8192];
        short8 af[4], bf[4];
#pragma unroll
        for (int f = 0; f < 4; ++f) {
            const int ar = wr * 64 + f * 16 + lrow;
            af[f] = *(const short8*)&Lb[0 * 4096 + ar * 32 + ((kh ^ (ar & 3)) * 8)];
            const int br = wc * 64 + f * 16 + lrow;
            bf[f] = *(const short8*)&Lb[1 * 4096 + br * 32 + ((kh ^ (br & 3)) * 8)];
        }
#pragma unroll
        for (int fm = 0; fm < 4; ++fm)
#pragma unroll
            for (int fn = 0; fn < 4; ++fn)
                acc[fm][fn] = __builtin_amdgcn_mfma_f32_16x16x32_bf16(
                    af[fm], bf[fn], acc[fm][fn], 0, 0, 0);
        // ds_reads of buf[cur] must complete before next iter re-stages it
        asm volatile("s_waitcnt lgkmcnt(0)" ::: "memory");
        __builtin_amdgcn_s_barrier();
        asm volatile("" ::: "memory");
    }
#undef STAGE

    // epilogue: row = row0+wr*64+fm*16+kh*4+m, col = col0+wc*64+fn*16+lrow
#pragma unroll
    for (int fm = 0; fm < 4; ++fm) {
#pragma unroll
        for (int fn = 0; fn < 4; ++fn) {
#pragma unroll
            for (int m = 0; m < 4; ++m) {
                const int row = row0 + wr * 64 + fm * 16 + kh * 4 + m;
                const int col = col0 + wc * 64 + fn * 16 + lrow;
                const float f = acc[fm][fn][m];
                if (SPLIT) {
                    Dhi[(size_t)row * NN + col] = f2bf(f);
                } else {
                    Dout[(size_t)row * NN + col] = f;
                }
            }
        }
    }
}

extern "C" void kernel_launch(void* const* d_in, const int* in_sizes, int n_in,
                              void* d_out, int out_size, void* d_ws, size_t ws_size,
                              hipStream_t stream) {
    const float* x = (const float*)d_in[0];
    float* out = (float*)d_out;
    u16* Chi  = (u16*)d_ws;
    u16* xthi = Chi  + (size_t)NN * NN;
    u16* Thi  = xthi + (size_t)NN * NN;

    gen_tables<<<dim3((NN * (NN / 4)) / 256), 256, 0, stream>>>(Chi);
    transpose_round<<<dim3(NN / 64, NN / 64), 256, 0, stream>>>(x, xthi);

    dim3 grid(NN / 128, NN / 128);
    // GEMM1: T = Ctab @ x       (A=Ctab, B(n-major)=x^T) -> bf16 T
    gemm_bf16<1><<<grid, 256, 0, stream>>>(Chi, xthi, nullptr, Thi);
    // GEMM2: out = T @ Ctab^T   (A=T, B(n-major)=Ctab)   -> fp32 out
    gemm_bf16<0><<<grid, 256, 0, stream>>>(Thi, Chi, out, nullptr);
}

// Round 12
// 375.343 us; speedup vs baseline: 8.5761x; 1.1438x over previous
//
#include <hip/hip_runtime.h>
#include <math.h>

#define NN 4096
#define NT 128   // K tiles of 32

typedef __attribute__((ext_vector_type(8))) short short8;
typedef __attribute__((ext_vector_type(4))) float f32x4;
typedef unsigned int uint32;
typedef unsigned short u16;

__device__ __forceinline__ u16 f2bf(float f) {
    uint32 u = __float_as_uint(f);
    return (u16)((u + 0x7FFFu + ((u >> 16) & 1u)) >> 16);  // RNE
}

__device__ __forceinline__ void gload_lds16(const u16* g, u16* l) {
    __builtin_amdgcn_global_load_lds(
        (const __attribute__((address_space(1))) uint32*)g,
        (__attribute__((address_space(3))) uint32*)l, 16, 0, 0);
}

// ---- cosine table, bf16 (validated expression order, hi only) ----
// Ctab[r][c] = cos(W*(2c+1)*r); A-operand in GEMM1 (r=u,c=i),
// n-major B-operand in GEMM2 (r=v,c=j).
__global__ __launch_bounds__(256) void gen_tables(u16* __restrict__ Chi) {
    const int idx = blockIdx.x * 256 + threadIdx.x;
    const int r  = idx >> 10;
    const int c4 = (idx & 1023) << 2;
    const float W  = (float)(M_PI / 8192.0);
    const float fr = (float)r;
    ushort4 hv;
    u16* hp = (u16*)&hv;
#pragma unroll
    for (int t = 0; t < 4; ++t) {
        const int c = c4 + t;
        const float wc = W * (float)(2 * c + 1);
        hp[t] = f2bf(cosf(wc * fr));
    }
    *(ushort4*)(Chi + (size_t)r * NN + c4) = hv;
}

// ---- transpose + bf16 round of x: xt[j][i] = rnd(x[i][j]) ----
__global__ __launch_bounds__(256) void transpose_round(const float* __restrict__ x,
                                                       u16* __restrict__ xthi) {
    __shared__ float tile[64][65];
    const int tid = threadIdx.x;
    const int r0 = blockIdx.y * 64, c0 = blockIdx.x * 64;
    const int tr = tid >> 4, tc4 = (tid & 15) * 4;
#pragma unroll
    for (int p = 0; p < 4; ++p) {
        const int row = p * 16 + tr;
        const float4 v = *(const float4*)(x + (size_t)(r0 + row) * NN + c0 + tc4);
        tile[row][tc4 + 0] = v.x;
        tile[row][tc4 + 1] = v.y;
        tile[row][tc4 + 2] = v.z;
        tile[row][tc4 + 3] = v.w;
    }
    __syncthreads();
#pragma unroll
    for (int p = 0; p < 4; ++p) {
        const int jj = p * 16 + tr;
        ushort4 hv;
        u16* hp = (u16*)&hv;
#pragma unroll
        for (int q = 0; q < 4; ++q)
            hp[q] = f2bf(tile[tc4 + q][jj]);
        *(ushort4*)(xthi + (size_t)(c0 + jj) * NN + r0 + tc4) = hv;
    }
}

// ---- pure-bf16 GEMM: D = A (MxK row-major) * B^T (B stored n-major [n][k]).
// 256x256 tile, BK=32, 8 waves (2Mx4N), 128x64/wave of 16x16x32 MFMA.
// Round-8-verified loop ledger (dbuf, 4 loads/stage, vmcnt(4)/vmcnt(0) final),
// scaled up: LDS traffic/MFMA halved -> MFMA pipe becomes the binding
// resource. Swizzle kh^((row>>2)&3): 16 lanes -> 8 bank-bases -> 2-way (free).
template <int SPLIT>
__global__ __launch_bounds__(512, 2) void gemm_bf16(
    const u16* __restrict__ A, const u16* __restrict__ B,
    float* __restrict__ Dout, u16* __restrict__ Dhi) {
    __shared__ u16 lds[2 * 2 * 8192];   // [buf][A|B][256*32] = 64 KB
    const int tid = threadIdx.x;        // 0..511
    const int w = tid >> 6, l = tid & 63;
    const int wr = w >> 2, wc = w & 3;  // 2 x 4 wave grid
    const int lrow = l & 15, kh = l >> 4;
    const int row0 = blockIdx.y * 256, col0 = blockIdx.x * 256;

    f32x4 acc[8][4];
#pragma unroll
    for (int i = 0; i < 8; ++i)
#pragma unroll
        for (int j = 0; j < 4; ++j)
            acc[i][j] = (f32x4){0.f, 0.f, 0.f, 0.f};

    // staging: 16B slot v = s*512+tid; row=v>>2; phys chunk (v&3) holds
    // logical k-chunk ((v&3) ^ ((row>>2)&3)); read side XORs the same way.
    const int v0 = tid, v1 = tid + 512;
    const int r0s = v0 >> 2, c0s = ((v0 & 3) ^ ((v0 >> 4) & 3)) * 8;
    const int r1s = v1 >> 2, c1s = ((v1 & 3) ^ ((v1 >> 4) & 3)) * 8;
    const u16* pA0 = A + (size_t)(row0 + r0s) * NN + c0s;
    const u16* pA1 = A + (size_t)(row0 + r1s) * NN + c1s;
    const u16* pB0 = B + (size_t)(col0 + r0s) * NN + c0s;
    const u16* pB1 = B + (size_t)(col0 + r1s) * NN + c1s;
    const int d0 = (0 * 512 + w * 64) * 8;   // wave-uniform LDS dest (u16 idx)
    const int d1 = (1 * 512 + w * 64) * 8;

#define STAGE(buf, koff)                                                     \
    do {                                                                     \
        u16* Lb = &lds[(buf) * 16384];                                       \
        gload_lds16(pA0 + (koff), Lb + 0 * 8192 + d0);                       \
        gload_lds16(pA1 + (koff), Lb + 0 * 8192 + d1);                       \
        gload_lds16(pB0 + (koff), Lb + 1 * 8192 + d0);                       \
        gload_lds16(pB1 + (koff), Lb + 1 * 8192 + d1);                       \
    } while (0)

    STAGE(0, 0);   // prologue: tile 0 -> buf 0

    for (int t = 0; t < NT; ++t) {
        const int cur = t & 1;
        if (t + 1 < NT) {
            STAGE(cur ^ 1, (t + 1) * 32);
            // retire tile t's 4 loads; keep tile t+1's 4 in flight
            asm volatile("s_waitcnt vmcnt(4)" ::: "memory");
        } else {
            // final tile: nothing behind it -> full drain (round-4 lesson)
            asm volatile("s_waitcnt vmcnt(0)" ::: "memory");
        }
        __builtin_amdgcn_s_barrier();
        asm volatile("" ::: "memory");

        const u16* Lb = &lds[cur * 16384];
        short8 af[8], bf[4];
#pragma unroll
        for (int fm = 0; fm < 8; ++fm) {
            const int ar = wr * 128 + fm * 16 + lrow;
            af[fm] = *(const short8*)&Lb[0 * 8192 + ar * 32 + ((kh ^ ((ar >> 2) & 3)) * 8)];
        }
#pragma unroll
        for (int fn = 0; fn < 4; ++fn) {
            const int br = wc * 64 + fn * 16 + lrow;
            bf[fn] = *(const short8*)&Lb[1 * 8192 + br * 32 + ((kh ^ ((br >> 2) & 3)) * 8)];
        }
#pragma unroll
        for (int fm = 0; fm < 8; ++fm)
#pragma unroll
            for (int fn = 0; fn < 4; ++fn)
                acc[fm][fn] = __builtin_amdgcn_mfma_f32_16x16x32_bf16(
                    af[fm], bf[fn], acc[fm][fn], 0, 0, 0);
        // ds_reads of buf[cur] must complete before next iter re-stages it
        asm volatile("s_waitcnt lgkmcnt(0)" ::: "memory");
        __builtin_amdgcn_s_barrier();
        asm volatile("" ::: "memory");
    }
#undef STAGE

    // epilogue: row = row0+wr*128+fm*16+kh*4+m, col = col0+wc*64+fn*16+lrow
#pragma unroll
    for (int fm = 0; fm < 8; ++fm) {
#pragma unroll
        for (int fn = 0; fn < 4; ++fn) {
#pragma unroll
            for (int m = 0; m < 4; ++m) {
                const int row = row0 + wr * 128 + fm * 16 + kh * 4 + m;
                const int col = col0 + wc * 64 + fn * 16 + lrow;
                const float f = acc[fm][fn][m];
                if (SPLIT) {
                    Dhi[(size_t)row * NN + col] = f2bf(f);
                } else {
                    Dout[(size_t)row * NN + col] = f;
                }
            }
        }
    }
}

extern "C" void kernel_launch(void* const* d_in, const int* in_sizes, int n_in,
                              void* d_out, int out_size, void* d_ws, size_t ws_size,
                              hipStream_t stream) {
    const float* x = (const float*)d_in[0];
    float* out = (float*)d_out;
    u16* Chi  = (u16*)d_ws;
    u16* xthi = Chi  + (size_t)NN * NN;
    u16* Thi  = xthi + (size_t)NN * NN;

    gen_tables<<<dim3((NN * (NN / 4)) / 256), 256, 0, stream>>>(Chi);
    transpose_round<<<dim3(NN / 64, NN / 64), 256, 0, stream>>>(x, xthi);

    dim3 grid(NN / 256, NN / 256);
    // GEMM1: T = Ctab @ x       (A=Ctab, B(n-major)=x^T) -> bf16 T
    gemm_bf16<1><<<grid, 512, 0, stream>>>(Chi, xthi, nullptr, Thi);
    // GEMM2: out = T @ Ctab^T   (A=T, B(n-major)=Ctab)   -> fp32 out
    gemm_bf16<0><<<grid, 512, 0, stream>>>(Thi, Chi, out, nullptr);
}

// Round 13
// 370.488 us; speedup vs baseline: 8.6885x; 1.0131x over previous
//
#include <hip/hip_runtime.h>
#include <math.h>

#define NN 4096
#define NTILES 64   // K tiles of 64

typedef __attribute__((ext_vector_type(8))) short short8;
typedef __attribute__((ext_vector_type(4))) float f32x4;
typedef unsigned int uint32;
typedef unsigned short u16;

__device__ __forceinline__ u16 f2bf(float f) {
    uint32 u = __float_as_uint(f);
    return (u16)((u + 0x7FFFu + ((u >> 16) & 1u)) >> 16);  // RNE
}

__device__ __forceinline__ void gload_lds16(const u16* g, u16* l) {
    __builtin_amdgcn_global_load_lds(
        (const __attribute__((address_space(1))) uint32*)g,
        (__attribute__((address_space(3))) uint32*)l, 16, 0, 0);
}

#define BAR()   do { __builtin_amdgcn_s_barrier(); asm volatile("" ::: "memory"); } while (0)
#define LGKM0() asm volatile("s_waitcnt lgkmcnt(0)" ::: "memory")

// ---- cosine table, bf16 (validated expression order, hi only) ----
__global__ __launch_bounds__(256) void gen_tables(u16* __restrict__ Chi) {
    const int idx = blockIdx.x * 256 + threadIdx.x;
    const int r  = idx >> 10;
    const int c4 = (idx & 1023) << 2;
    const float W  = (float)(M_PI / 8192.0);
    const float fr = (float)r;
    ushort4 hv;
    u16* hp = (u16*)&hv;
#pragma unroll
    for (int t = 0; t < 4; ++t) {
        const int c = c4 + t;
        const float wc = W * (float)(2 * c + 1);
        hp[t] = f2bf(cosf(wc * fr));
    }
    *(ushort4*)(Chi + (size_t)r * NN + c4) = hv;
}

// ---- transpose + bf16 round of x (validated) ----
__global__ __launch_bounds__(256) void transpose_round(const float* __restrict__ x,
                                                       u16* __restrict__ xthi) {
    __shared__ float tile[64][65];
    const int tid = threadIdx.x;
    const int r0 = blockIdx.y * 64, c0 = blockIdx.x * 64;
    const int tr = tid >> 4, tc4 = (tid & 15) * 4;
#pragma unroll
    for (int p = 0; p < 4; ++p) {
        const int row = p * 16 + tr;
        const float4 v = *(const float4*)(x + (size_t)(r0 + row) * NN + c0 + tc4);
        tile[row][tc4 + 0] = v.x;
        tile[row][tc4 + 1] = v.y;
        tile[row][tc4 + 2] = v.z;
        tile[row][tc4 + 3] = v.w;
    }
    __syncthreads();
#pragma unroll
    for (int p = 0; p < 4; ++p) {
        const int jj = p * 16 + tr;
        ushort4 hv;
        u16* hp = (u16*)&hv;
#pragma unroll
        for (int q = 0; q < 4; ++q)
            hp[q] = f2bf(tile[tc4 + q][jj]);
        *(ushort4*)(xthi + (size_t)(c0 + jj) * NN + r0 + tc4) = hv;
    }
}

// ---- pure-bf16 GEMM: D = A (MxK row-major) * B^T (B stored n-major [n][k]).
// 256x256 tile, BK=64, 8 waves (2Mx4N), 128x64/wave of 16x16x32 MFMA.
// 4 phases x 16 MFMA per K-tile (T3) with setprio (T5); counted vmcnt(4)
// ledger (T4): tile j+1's A staged before gate, B after phase 0; full-period
// 8-chunk swizzle chunk' = (ks*4+kh) ^ (row&7) on both sides (T2, rule #21).
template <int SPLIT>
__global__ __launch_bounds__(512, 2) void gemm_bf16(
    const u16* __restrict__ A, const u16* __restrict__ B,
    float* __restrict__ Dout, u16* __restrict__ Dhi) {
    __shared__ u16 lds[2 * 2 * 16384];   // [buf][A|B][256*64] = 128 KB
    const int tid = threadIdx.x;         // 0..511
    const int w = tid >> 6, l = tid & 63;
    const int wr = w >> 2, wc = w & 3;   // 2M x 4N wave grid
    const int lrow = l & 15, kh = l >> 4;
    const int row0 = blockIdx.y * 256, col0 = blockIdx.x * 256;

    f32x4 acc[8][4];
#pragma unroll
    for (int i = 0; i < 8; ++i)
#pragma unroll
        for (int j = 0; j < 4; ++j)
            acc[i][j] = (f32x4){0.f, 0.f, 0.f, 0.f};

    // staging: slot v = s*512+tid; row = v>>3 (128B rows), phys chunk v&7
    // holds logical chunk (v&7) ^ (row&7). rows advance 64 per round s.
    const int rA = tid >> 3;                                // 0..63
    const int c8 = (((tid & 7) ^ ((tid >> 3) & 7)) * 8);    // pre-swizzled src
    const u16* pA = A + (size_t)(row0 + rA) * NN + c8;
    const u16* pB = B + (size_t)(col0 + rA) * NN + c8;

#define STAGE_A(kt, buf)                                                     \
    do {                                                                     \
        u16* Ld = &lds[(buf) * 32768 + 0 * 16384 + w * 512];                 \
        const u16* gs = pA + (size_t)(kt) * 64;                              \
        _Pragma("unroll") for (int s = 0; s < 4; ++s)                        \
            gload_lds16(gs + (size_t)s * 64 * NN, Ld + s * 4096);            \
    } while (0)
#define STAGE_B(kt, buf)                                                     \
    do {                                                                     \
        u16* Ld = &lds[(buf) * 32768 + 1 * 16384 + w * 512];                 \
        const u16* gs = pB + (size_t)(kt) * 64;                              \
        _Pragma("unroll") for (int s = 0; s < 4; ++s)                        \
            gload_lds16(gs + (size_t)s * 64 * NN, Ld + s * 4096);            \
    } while (0)

    // fragment readers: row*64 u16 per row; chunk' = (ks*4+kh)^(row&7)
    auto rdA = [&](short8* d, const u16* L, int rbase, int ks) {
#pragma unroll
        for (int f = 0; f < 4; ++f) {
            const int r = rbase + f * 16 + lrow;
            d[f] = *(const short8*)&L[r * 64 + (((ks * 4 + kh) ^ (r & 7)) * 8)];
        }
    };
    auto rdB = [&](short8* d, const u16* L, int rbase, int ks) {
#pragma unroll
        for (int f = 0; f < 4; ++f) {
            const int r = rbase + f * 16 + lrow;
            d[f] = *(const short8*)&L[r * 64 + (((ks * 4 + kh) ^ (r & 7)) * 8)];
        }
    };

    STAGE_A(0, 0);
    STAGE_B(0, 0);   // prologue: tile 0 -> buf0 (8 loads out)

    for (int j = 0; j < NTILES; ++j) {
        const int cur = j & 1;
        if (j + 1 < NTILES) {
            STAGE_A(j + 1, cur ^ 1);   // first 4 of tile j+1
            // retire tile j's 8 (oldest); keep tile j+1's 4 in flight
            asm volatile("s_waitcnt vmcnt(4)" ::: "memory");
        } else {
            asm volatile("s_waitcnt vmcnt(0)" ::: "memory");  // final drain
        }
        BAR();

        const u16* LA = &lds[cur * 32768];
        const u16* LB = &lds[cur * 32768 + 16384];
        short8 a[4], b[4];

        // ---- phase 0: ks=0, fm 0-3 (8 reads) ----
        rdA(a, LA, wr * 128, 0);
        rdB(b, LB, wc * 64, 0);
        BAR(); LGKM0();
        __builtin_amdgcn_s_setprio(1);
#pragma unroll
        for (int fm = 0; fm < 4; ++fm)
#pragma unroll
            for (int fn = 0; fn < 4; ++fn)
                acc[fm][fn] = __builtin_amdgcn_mfma_f32_16x16x32_bf16(
                    a[fm], b[fn], acc[fm][fn], 0, 0, 0);
        __builtin_amdgcn_s_setprio(0);
        BAR();
        if (j + 1 < NTILES) STAGE_B(j + 1, cur ^ 1);   // last 4 of tile j+1

        // ---- phase 1: ks=0, fm 4-7 (4 reads, B reused) ----
        rdA(a, LA, wr * 128 + 64, 0);
        BAR(); LGKM0();
        __builtin_amdgcn_s_setprio(1);
#pragma unroll
        for (int fm = 0; fm < 4; ++fm)
#pragma unroll
            for (int fn = 0; fn < 4; ++fn)
                acc[4 + fm][fn] = __builtin_amdgcn_mfma_f32_16x16x32_bf16(
                    a[fm], b[fn], acc[4 + fm][fn], 0, 0, 0);
        __builtin_amdgcn_s_setprio(0);
        BAR();

        // ---- phase 2: ks=1, fm 0-3 (8 reads) ----
        rdA(a, LA, wr * 128, 1);
        rdB(b, LB, wc * 64, 1);
        BAR(); LGKM0();
        __builtin_amdgcn_s_setprio(1);
#pragma unroll
        for (int fm = 0; fm < 4; ++fm)
#pragma unroll
            for (int fn = 0; fn < 4; ++fn)
                acc[fm][fn] = __builtin_amdgcn_mfma_f32_16x16x32_bf16(
                    a[fm], b[fn], acc[fm][fn], 0, 0, 0);
        __builtin_amdgcn_s_setprio(0);
        BAR();

        // ---- phase 3: ks=1, fm 4-7 (4 reads, B reused) ----
        rdA(a, LA, wr * 128 + 64, 1);
        BAR(); LGKM0();
        __builtin_amdgcn_s_setprio(1);
#pragma unroll
        for (int fm = 0; fm < 4; ++fm)
#pragma unroll
            for (int fn = 0; fn < 4; ++fn)
                acc[4 + fm][fn] = __builtin_amdgcn_mfma_f32_16x16x32_bf16(
                    a[fm], b[fn], acc[4 + fm][fn], 0, 0, 0);
        __builtin_amdgcn_s_setprio(0);
        // all this wave's ds_reads of buf[cur] drained (LGKM0 above);
        // trailing barrier makes that true block-wide before next iter's
        // STAGE_A may land into buf[cur^1... buf reuse two iters out.
        LGKM0();
        BAR();
    }
#undef STAGE_A
#undef STAGE_B

    // epilogue: row = row0+wr*128+fm*16+kh*4+m, col = col0+wc*64+fn*16+lrow
#pragma unroll
    for (int fm = 0; fm < 8; ++fm) {
#pragma unroll
        for (int fn = 0; fn < 4; ++fn) {
#pragma unroll
            for (int m = 0; m < 4; ++m) {
                const int row = row0 + wr * 128 + fm * 16 + kh * 4 + m;
                const int col = col0 + wc * 64 + fn * 16 + lrow;
                const float f = acc[fm][fn][m];
                if (SPLIT) {
                    Dhi[(size_t)row * NN + col] = f2bf(f);
                } else {
                    Dout[(size_t)row * NN + col] = f;
                }
            }
        }
    }
}

extern "C" void kernel_launch(void* const* d_in, const int* in_sizes, int n_in,
                              void* d_out, int out_size, void* d_ws, size_t ws_size,
                              hipStream_t stream) {
    const float* x = (const float*)d_in[0];
    float* out = (float*)d_out;
    u16* Chi  = (u16*)d_ws;
    u16* xthi = Chi  + (size_t)NN * NN;
    u16* Thi  = xthi + (size_t)NN * NN;

    gen_tables<<<dim3((NN * (NN / 4)) / 256), 256, 0, stream>>>(Chi);
    transpose_round<<<dim3(NN / 64, NN / 64), 256, 0, stream>>>(x, xthi);

    dim3 grid(NN / 256, NN / 256);
    // GEMM1: T = Ctab @ x       (A=Ctab, B(n-major)=x^T) -> bf16 T
    gemm_bf16<1><<<grid, 512, 0, stream>>>(Chi, xthi, nullptr, Thi);
    // GEMM2: out = T @ Ctab^T   (A=T, B(n-major)=Ctab)   -> fp32 out
    gemm_bf16<0><<<grid, 512, 0, stream>>>(Thi, Chi, out, nullptr);
}